// Round 3
// baseline (663.674 us; speedup 1.0000x reference)
//
#include <hip/hip_runtime.h>
#include <stdint.h>

#define DEV static __device__ __forceinline__

typedef __attribute__((ext_vector_type(8))) short bf16x8;
typedef __attribute__((ext_vector_type(4))) float f32x4;

DEV unsigned short f2b(float f){
  union { float f; unsigned int u; } v; v.f = f;
  return (unsigned short)((v.u + 0x7FFFu + ((v.u >> 16) & 1u)) >> 16);
}

#define SWZ(v, pat) __int_as_float(__builtin_amdgcn_ds_swizzle(__float_as_int(v), pat))

// ---------------- f32 -> bf16 convert ----------------
__global__ __launch_bounds__(256) void cvt_f32_bf16(const float* __restrict__ in,
                                                    unsigned short* __restrict__ out, int n4){
  int stride = gridDim.x * blockDim.x;
  for (int i = blockIdx.x * blockDim.x + threadIdx.x; i < n4; i += stride){
    float4 v = ((const float4*)in)[i];
    ushort4 o = make_ushort4(f2b(v.x), f2b(v.y), f2b(v.z), f2b(v.w));
    ((ushort4*)out)[i] = o;
  }
}

// ---------------- bt-GEMM: C[M,N] = A[M,K] * B[N,K]^T, 128x128 tile ----------------
// MODE 0: QKV gemm, fused RoPE epilogue -> Q,K,V [B,H,L,HD] bf16 (Q pre-scaled 1/8)
// MODE 1: proj gemm, f32 output [M,N]
template<int MODE>
__global__ __launch_bounds__(256, 2) void gemm_bt(
    const unsigned short* __restrict__ A,
    const unsigned short* __restrict__ Bw,
    int K, int nbn, int N,
    const float* __restrict__ cosp, const float* __restrict__ sinp,
    unsigned short* __restrict__ Qo, unsigned short* __restrict__ Ko,
    unsigned short* __restrict__ Vo, float* __restrict__ Cout)
{
  __shared__ __align__(16) unsigned char lds[32768]; // A tile @0 (16KB), B tile @16384
  const int t = threadIdx.x;
  const int wid = t >> 6, lane = t & 63;
  const int l15 = lane & 15, l4 = lane >> 4;
  const int bm = blockIdx.x / nbn, bn = blockIdx.x % nbn;
  const int m0 = bm * 128, n0 = bn * 128;
  const int mb = (wid >> 1) * 64, nb = (wid & 1) * 64;

  f32x4 acc[4][4];
  #pragma unroll
  for (int i = 0; i < 4; ++i)
    #pragma unroll
    for (int j = 0; j < 4; ++j)
      acc[i][j] = (f32x4){0.f, 0.f, 0.f, 0.f};

  for (int k0 = 0; k0 < K; k0 += 64){
    __syncthreads();
    #pragma unroll
    for (int i = 0; i < 4; ++i){
      int c = i * 256 + t;            // 0..1023 : 128 rows x 8 chunks(16B)
      int row = c >> 3, ch = c & 7;
      int sw = row * 128 + ((ch * 16) ^ ((row & 7) << 4));
      *(uint4*)(lds + sw)         = *(const uint4*)(A  + (size_t)(m0 + row) * K + k0 + ch * 8);
      *(uint4*)(lds + 16384 + sw) = *(const uint4*)(Bw + (size_t)(n0 + row) * K + k0 + ch * 8);
    }
    __syncthreads();
    #pragma unroll
    for (int ks = 0; ks < 2; ++ks){
      bf16x8 af[4], bfr[4];
      #pragma unroll
      for (int mi = 0; mi < 4; ++mi){
        int r = mb + mi * 16 + l15, ch = ks * 4 + l4;
        af[mi] = *(const bf16x8*)(lds + r * 128 + ((ch * 16) ^ ((r & 7) << 4)));
      }
      #pragma unroll
      for (int ni = 0; ni < 4; ++ni){
        int r = nb + ni * 16 + l15, ch = ks * 4 + l4;
        bfr[ni] = *(const bf16x8*)(lds + 16384 + r * 128 + ((ch * 16) ^ ((r & 7) << 4)));
      }
      #pragma unroll
      for (int mi = 0; mi < 4; ++mi)
        #pragma unroll
        for (int ni = 0; ni < 4; ++ni)
          acc[mi][ni] = __builtin_amdgcn_mfma_f32_16x16x32_bf16(af[mi], bfr[ni], acc[mi][ni], 0, 0, 0);
    }
  }

  if (MODE == 1){
    #pragma unroll
    for (int mi = 0; mi < 4; ++mi)
      #pragma unroll
      for (int ni = 0; ni < 4; ++ni)
        #pragma unroll
        for (int j = 0; j < 4; ++j){
          int m = m0 + mb + mi * 16 + l4 * 4 + j;
          int n = n0 + nb + ni * 16 + l15;
          Cout[(size_t)m * N + n] = acc[mi][ni][j];
        }
  } else {
    // RoPE epilogue. e in [0,6144): which = e>>11 (0=q,1=k,2=v), h=(e>>6)&31, d=e&63.
    // Wave spans 64 aligned cols => one head per wave; partner col d^32 lives in frag ni^2, same lane.
    #pragma unroll
    for (int ni = 0; ni < 4; ++ni){
      int e = n0 + nb + ni * 16 + l15;
      int which = e >> 11;
      int h = (e >> 6) & 31;
      int d = e & 63;
      unsigned short* dst = (which == 0) ? Qo : (which == 1) ? Ko : Vo;
      #pragma unroll
      for (int mi = 0; mi < 4; ++mi)
        #pragma unroll
        for (int j = 0; j < 4; ++j){
          int m = m0 + mb + mi * 16 + l4 * 4 + j;   // token index = b*2048 + l
          int b = m >> 11, l = m & 2047;
          float v = acc[mi][ni][j];
          float outv;
          if (which == 2){
            outv = v;
          } else {
            float pv = acc[mi][ni ^ 2][j];          // partner column d^32
            size_t ci = (size_t)(b * 2048 + l) * 64 + d;
            outv = v * cosp[ci] + ((d < 32) ? -pv : pv) * sinp[ci];
            if (which == 0) outv *= 0.125f;         // fold 1/sqrt(64)
          }
          dst[(size_t)((b * 32 + h) * 2048 + l) * 64 + d] = f2b(outv);
        }
    }
  }
}

// ---------------- V [BH, L, 64] -> Vt [BH, 64, L] ----------------
__global__ __launch_bounds__(256) void transpose_v(const unsigned short* __restrict__ V,
                                                   unsigned short* __restrict__ Vt){
  __shared__ unsigned short tile[64][72];
  int bh = blockIdx.x >> 5;
  int l0 = (blockIdx.x & 31) * 64;
  int t = threadIdx.x;
  #pragma unroll
  for (int i = 0; i < 2; ++i){
    int c = i * 256 + t;
    int row = c >> 3, ch = c & 7;
    uint4 v = *(const uint4*)(V + ((size_t)bh * 2048 + l0 + row) * 64 + ch * 8);
    const unsigned short* p = (const unsigned short*)&v;
    #pragma unroll
    for (int k = 0; k < 8; ++k) tile[row][ch * 8 + k] = p[k];
  }
  __syncthreads();
  #pragma unroll
  for (int i = 0; i < 2; ++i){
    int c = i * 256 + t;
    int drow = c >> 3, ch = c & 7;
    unsigned short tmp[8];
    #pragma unroll
    for (int k = 0; k < 8; ++k) tmp[k] = tile[ch * 8 + k][drow];
    *(uint4*)(Vt + ((size_t)bh * 64 + drow) * 2048 + l0 + ch * 8) = *(const uint4*)tmp;
  }
}

// ---------------- flash attention (causal) ----------------
// 512 threads = 8 waves x 32 q-rows (256-row q-block). K/Vt tiles (8KB each)
// cooperatively staged into double-buffered LDS; next tile's global loads issue
// before compute, ds_write after (T14 async split), one barrier per k-tile.
// Grid = 64 bh x 8 qb = 512 blocks = exactly 2/CU, all resident at once.
__global__ __launch_bounds__(512, 4) void attn_fwd(
    const unsigned short* __restrict__ Q, const unsigned short* __restrict__ K,
    const unsigned short* __restrict__ Vt, unsigned short* __restrict__ Y)
{
  __shared__ __align__(16) unsigned char kvb[2][16384];  // [buf]: K tile @0, V tile @8192 (64x64 bf16 each, swizzled)
  __shared__ __align__(16) unsigned char plds[8][4096];  // per-wave P tile [32][64] bf16, swizzled
  int idx = blockIdx.x;
  int bh = idx >> 3;                     // 8 blocks per bh, contiguous (L2 locality)
  static const int qmap[8] = {7, 0, 6, 1, 5, 2, 4, 3};  // interleave heavy/light
  int qb = qmap[idx & 7];
  int b = bh >> 5, h = bh & 31;
  int t = threadIdx.x, wid = t >> 6, lane = t & 63;
  int l15 = lane & 15, l4 = lane >> 4;
  int q0 = qb * 256 + wid * 32;          // 32 q-rows per wave
  const unsigned short* Qb = Q  + (size_t)bh * 2048 * 64;
  const unsigned short* Kb = K  + (size_t)bh * 2048 * 64;
  const unsigned short* Vb = Vt + (size_t)bh * 64 * 2048;
  unsigned char* myp = plds[wid];

  // staging map: 512 threads cover a 64x64 bf16 tile as 64 rows x 8 chunks(16B)
  int srow = t >> 3, sch = t & 7;
  int soff = srow * 128 + ((sch * 16) ^ ((srow & 7) << 4));
  const unsigned short* gk = Kb + (size_t)srow * 64 + sch * 8;    // + kv0*64 per tile
  const unsigned short* gv = Vb + (size_t)srow * 2048 + sch * 8;  // + kv0 per tile

  // Q fragments (one-time)
  bf16x8 aq[2][2];
  #pragma unroll
  for (int mi = 0; mi < 2; ++mi)
    #pragma unroll
    for (int ks = 0; ks < 2; ++ks)
      aq[mi][ks] = *(const bf16x8*)(Qb + (size_t)(q0 + mi * 16 + l15) * 64 + ks * 32 + l4 * 8);

  f32x4 acc[2][4];
  #pragma unroll
  for (int mi = 0; mi < 2; ++mi)
    #pragma unroll
    for (int nd = 0; nd < 4; ++nd)
      acc[mi][nd] = (f32x4){0.f, 0.f, 0.f, 0.f};
  float mrow[2][4], lrow[2][4];
  #pragma unroll
  for (int mi = 0; mi < 2; ++mi)
    #pragma unroll
    for (int j = 0; j < 4; ++j){ mrow[mi][j] = -3e38f; lrow[mi][j] = 0.f; }

  int my_nkt = ((q0 + 31) >> 6) + 1;     // k-tiles this wave needs
  int nkt_blk = 4 * qb + 4;              // k-tiles the block stages

  // prologue: stage tile 0
  {
    uint4 k0 = *(const uint4*)gk;
    uint4 v0 = *(const uint4*)gv;
    *(uint4*)(kvb[0] + soff) = k0;
    *(uint4*)(kvb[0] + 8192 + soff) = v0;
  }
  __syncthreads();
  int cur = 0;

  for (int kt = 0; kt < nkt_blk; ++kt){
    int kv0 = kt * 64;
    // issue next tile's global loads (consumed after compute -> latency hidden)
    uint4 nk, nv;
    bool more = (kt + 1 < nkt_blk);
    if (more){
      nk = *(const uint4*)(gk + (size_t)(kv0 + 64) * 64);
      nv = *(const uint4*)(gv + (kv0 + 64));
    }
    if (kt < my_nkt){
      const unsigned char* kb = kvb[cur];
      const unsigned char* vb = kvb[cur] + 8192;
      // ---- QK^T from LDS ----
      f32x4 s[2][4];
      #pragma unroll
      for (int mi = 0; mi < 2; ++mi)
        #pragma unroll
        for (int ni = 0; ni < 4; ++ni)
          s[mi][ni] = (f32x4){0.f, 0.f, 0.f, 0.f};
      #pragma unroll
      for (int ks = 0; ks < 2; ++ks){
        bf16x8 bk[4];
        #pragma unroll
        for (int ni = 0; ni < 4; ++ni){
          int r = ni * 16 + l15, ch = ks * 4 + l4;
          bk[ni] = *(const bf16x8*)(kb + r * 128 + ((ch * 16) ^ ((r & 7) << 4)));
        }
        #pragma unroll
        for (int mi = 0; mi < 2; ++mi)
          #pragma unroll
          for (int ni = 0; ni < 4; ++ni)
            s[mi][ni] = __builtin_amdgcn_mfma_f32_16x16x32_bf16(aq[mi][ks], bk[ni], s[mi][ni], 0, 0, 0);
      }
      // ---- causal mask (last tile of this wave only) ----
      if (kt == my_nkt - 1){
        #pragma unroll
        for (int mi = 0; mi < 2; ++mi)
          #pragma unroll
          for (int ni = 0; ni < 4; ++ni)
            #pragma unroll
            for (int j = 0; j < 4; ++j){
              int kv = kv0 + ni * 16 + l15;
              int q  = q0 + mi * 16 + l4 * 4 + j;
              if (kv > q) s[mi][ni][j] = -1e30f;
            }
      }
      // ---- online softmax (16-lane ds_swizzle butterflies) ----
      float scl[2][4], rs[2][4];
      #pragma unroll
      for (int mi = 0; mi < 2; ++mi)
        #pragma unroll
        for (int j = 0; j < 4; ++j){
          float v = fmaxf(fmaxf(s[mi][0][j], s[mi][1][j]), fmaxf(s[mi][2][j], s[mi][3][j]));
          v = fmaxf(v, SWZ(v, 0x041F));
          v = fmaxf(v, SWZ(v, 0x081F));
          v = fmaxf(v, SWZ(v, 0x101F));
          v = fmaxf(v, SWZ(v, 0x201F));
          float nm = fmaxf(mrow[mi][j], v);
          scl[mi][j] = __expf(mrow[mi][j] - nm);
          mrow[mi][j] = nm;
          rs[mi][j] = 0.f;
        }
      #pragma unroll
      for (int mi = 0; mi < 2; ++mi)
        #pragma unroll
        for (int ni = 0; ni < 4; ++ni)
          #pragma unroll
          for (int j = 0; j < 4; ++j){
            float p = __expf(s[mi][ni][j] - mrow[mi][j]);
            s[mi][ni][j] = p;
            rs[mi][j] += p;
          }
      #pragma unroll
      for (int mi = 0; mi < 2; ++mi)
        #pragma unroll
        for (int j = 0; j < 4; ++j){
          float v = rs[mi][j];
          v += SWZ(v, 0x041F);
          v += SWZ(v, 0x081F);
          v += SWZ(v, 0x101F);
          v += SWZ(v, 0x201F);
          lrow[mi][j] = fmaf(lrow[mi][j], scl[mi][j], v);
        }
      #pragma unroll
      for (int mi = 0; mi < 2; ++mi)
        #pragma unroll
        for (int nd = 0; nd < 4; ++nd)
          #pragma unroll
          for (int j = 0; j < 4; ++j)
            acc[mi][nd][j] *= scl[mi][j];
      // ---- P (C-layout) -> per-wave LDS (swizzled), packed bf16 pairs ----
      #pragma unroll
      for (int mi = 0; mi < 2; ++mi)
        #pragma unroll
        for (int j = 0; j < 4; ++j){
          int r = mi * 16 + l4 * 4 + j;
          int sw = (r & 7) << 4;
          unsigned char* rowp = myp + r * 128;
          #pragma unroll
          for (int p2 = 0; p2 < 2; ++p2){
            unsigned int pk;
            asm("v_cvt_pk_bf16_f32 %0, %1, %2" : "=v"(pk) : "v"(s[mi][2 * p2][j]), "v"(s[mi][2 * p2 + 1][j]));
            *(unsigned short*)(rowp + ((p2 * 64      + 2 * l15) ^ sw)) = (unsigned short)pk;
            *(unsigned short*)(rowp + ((p2 * 64 + 32 + 2 * l15) ^ sw)) = (unsigned short)(pk >> 16);
          }
        }
      __threadfence_block();   // wave-local LDS write->read ordering
      // ---- PV from LDS ----
      #pragma unroll
      for (int ks2 = 0; ks2 < 2; ++ks2){
        bf16x8 ap[2], bv[4];
        #pragma unroll
        for (int mi = 0; mi < 2; ++mi){
          int r = mi * 16 + l15;
          ap[mi] = *(const bf16x8*)(myp + r * 128 + ((ks2 * 64 + l4 * 16) ^ ((r & 7) << 4)));
        }
        #pragma unroll
        for (int nd = 0; nd < 4; ++nd){
          int r = nd * 16 + l15, ch = ks2 * 4 + l4;
          bv[nd] = *(const bf16x8*)(vb + r * 128 + ((ch * 16) ^ ((r & 7) << 4)));
        }
        #pragma unroll
        for (int mi = 0; mi < 2; ++mi)
          #pragma unroll
          for (int nd = 0; nd < 4; ++nd)
            acc[mi][nd] = __builtin_amdgcn_mfma_f32_16x16x32_bf16(ap[mi], bv[nd], acc[mi][nd], 0, 0, 0);
      }
    }
    // write next tile into the other buffer (vmcnt drain lands here, late)
    if (more){
      *(uint4*)(kvb[cur ^ 1] + soff) = nk;
      *(uint4*)(kvb[cur ^ 1] + 8192 + soff) = nv;
    }
    __syncthreads();
    cur ^= 1;
  }

  // ---- epilogue ----
  #pragma unroll
  for (int mi = 0; mi < 2; ++mi){
    float inv[4];
    #pragma unroll
    for (int j = 0; j < 4; ++j) inv[j] = 1.f / lrow[mi][j];
    #pragma unroll
    for (int nd = 0; nd < 4; ++nd)
      #pragma unroll
      for (int j = 0; j < 4; ++j){
        int q = q0 + mi * 16 + l4 * 4 + j;
        int d = nd * 16 + l15;
        Y[(size_t)(b * 2048 + q) * 2048 + h * 64 + d] = f2b(acc[mi][nd][j] * inv[j]);
      }
  }
}

// ---------------- launch ----------------
extern "C" void kernel_launch(void* const* d_in, const int* in_sizes, int n_in,
                              void* d_out, int out_size, void* d_ws, size_t ws_size,
                              hipStream_t stream){
  (void)in_sizes; (void)n_in; (void)out_size; (void)ws_size;
  const float* x     = (const float*)d_in[0];
  const float* cosp  = (const float*)d_in[1];
  const float* sinp  = (const float*)d_in[2];
  const float* Wqkv  = (const float*)d_in[3];
  const float* Wproj = (const float*)d_in[4];
  float* out = (float*)d_out;
  char* ws = (char*)d_ws;

  // workspace layout (96 MiB, with aliasing):
  // [0,16M)   Xb  (bf16 x)            -> reused as Vt after GEMM1
  // [16,40M)  Wqkvb
  // [40,48M)  Wprojb
  // [48,64M)  Q   [64,80M) K   [80,96M) V -> reused as Y after transpose
  unsigned short* Xb  = (unsigned short*)(ws);
  unsigned short* Wqb = (unsigned short*)(ws + 16777216);
  unsigned short* Wpb = (unsigned short*)(ws + 41943040);
  unsigned short* Qb  = (unsigned short*)(ws + 50331648);
  unsigned short* Kb  = (unsigned short*)(ws + 67108864);
  unsigned short* Vb  = (unsigned short*)(ws + 83886080);
  unsigned short* Vtb = Xb;   // alias: Xb dead after GEMM1
  unsigned short* Yb  = Vb;   // alias: V dead after transpose

  cvt_f32_bf16<<<1536, 256, 0, stream>>>(x,     Xb,  2097152);  // 8.39M elems
  cvt_f32_bf16<<<1536, 256, 0, stream>>>(Wqkv,  Wqb, 3145728);  // 12.58M
  cvt_f32_bf16<<<1536, 256, 0, stream>>>(Wproj, Wpb, 1048576);  // 4.19M

  // QKV GEMM + RoPE: M=4096, N=6144, K=2048
  gemm_bt<0><<<32 * 48, 256, 0, stream>>>(Xb, Wqb, 2048, 48, 6144,
                                          cosp, sinp, Qb, Kb, Vb, nullptr);
  transpose_v<<<2048, 256, 0, stream>>>(Vb, Vtb);
  attn_fwd<<<512, 512, 0, stream>>>(Qb, Kb, Vtb, Yb);
  // out proj: M=4096, N=2048, K=2048, f32 out
  gemm_bt<1><<<32 * 16, 256, 0, stream>>>(Yb, Wpb, 2048, 16, 2048,
                                          nullptr, nullptr, nullptr, nullptr, nullptr, out);
}

// Round 4
// 342.796 us; speedup vs baseline: 1.9361x; 1.9361x over previous
//
#include <hip/hip_runtime.h>
#include <stdint.h>

#define DEV static __device__ __forceinline__

typedef __attribute__((ext_vector_type(8))) short bf16x8;
typedef __attribute__((ext_vector_type(4))) float f32x4;

DEV unsigned short f2b(float f){
  union { float f; unsigned int u; } v; v.f = f;
  return (unsigned short)((v.u + 0x7FFFu + ((v.u >> 16) & 1u)) >> 16);
}

#define SWZ(v, pat) __int_as_float(__builtin_amdgcn_ds_swizzle(__float_as_int(v), pat))

// ---------------- f32 -> bf16 convert ----------------
__global__ __launch_bounds__(256) void cvt_f32_bf16(const float* __restrict__ in,
                                                    unsigned short* __restrict__ out, int n4){
  int stride = gridDim.x * blockDim.x;
  for (int i = blockIdx.x * blockDim.x + threadIdx.x; i < n4; i += stride){
    float4 v = ((const float4*)in)[i];
    ushort4 o = make_ushort4(f2b(v.x), f2b(v.y), f2b(v.z), f2b(v.w));
    ((ushort4*)out)[i] = o;
  }
}

// ---------------- bt-GEMM: C[M,N] = A[M,K] * B[N,K]^T, 128x128 tile ----------------
// MODE 0: QKV gemm, fused RoPE epilogue -> Q,K,V [B,H,L,HD] bf16 (Q pre-scaled 1/8)
// MODE 1: proj gemm, f32 output [M,N]
template<int MODE>
__global__ __launch_bounds__(256, 2) void gemm_bt(
    const unsigned short* __restrict__ A,
    const unsigned short* __restrict__ Bw,
    int K, int nbn, int N,
    const float* __restrict__ cosp, const float* __restrict__ sinp,
    unsigned short* __restrict__ Qo, unsigned short* __restrict__ Ko,
    unsigned short* __restrict__ Vo, float* __restrict__ Cout)
{
  __shared__ __align__(16) unsigned char lds[32768]; // A tile @0 (16KB), B tile @16384
  const int t = threadIdx.x;
  const int wid = t >> 6, lane = t & 63;
  const int l15 = lane & 15, l4 = lane >> 4;
  const int bm = blockIdx.x / nbn, bn = blockIdx.x % nbn;
  const int m0 = bm * 128, n0 = bn * 128;
  const int mb = (wid >> 1) * 64, nb = (wid & 1) * 64;

  f32x4 acc[4][4];
  #pragma unroll
  for (int i = 0; i < 4; ++i)
    #pragma unroll
    for (int j = 0; j < 4; ++j)
      acc[i][j] = (f32x4){0.f, 0.f, 0.f, 0.f};

  for (int k0 = 0; k0 < K; k0 += 64){
    __syncthreads();
    #pragma unroll
    for (int i = 0; i < 4; ++i){
      int c = i * 256 + t;            // 0..1023 : 128 rows x 8 chunks(16B)
      int row = c >> 3, ch = c & 7;
      int sw = row * 128 + ((ch * 16) ^ ((row & 7) << 4));
      *(uint4*)(lds + sw)         = *(const uint4*)(A  + (size_t)(m0 + row) * K + k0 + ch * 8);
      *(uint4*)(lds + 16384 + sw) = *(const uint4*)(Bw + (size_t)(n0 + row) * K + k0 + ch * 8);
    }
    __syncthreads();
    #pragma unroll
    for (int ks = 0; ks < 2; ++ks){
      bf16x8 af[4], bfr[4];
      #pragma unroll
      for (int mi = 0; mi < 4; ++mi){
        int r = mb + mi * 16 + l15, ch = ks * 4 + l4;
        af[mi] = *(const bf16x8*)(lds + r * 128 + ((ch * 16) ^ ((r & 7) << 4)));
      }
      #pragma unroll
      for (int ni = 0; ni < 4; ++ni){
        int r = nb + ni * 16 + l15, ch = ks * 4 + l4;
        bfr[ni] = *(const bf16x8*)(lds + 16384 + r * 128 + ((ch * 16) ^ ((r & 7) << 4)));
      }
      #pragma unroll
      for (int mi = 0; mi < 4; ++mi)
        #pragma unroll
        for (int ni = 0; ni < 4; ++ni)
          acc[mi][ni] = __builtin_amdgcn_mfma_f32_16x16x32_bf16(af[mi], bfr[ni], acc[mi][ni], 0, 0, 0);
    }
  }

  if (MODE == 1){
    #pragma unroll
    for (int mi = 0; mi < 4; ++mi)
      #pragma unroll
      for (int ni = 0; ni < 4; ++ni)
        #pragma unroll
        for (int j = 0; j < 4; ++j){
          int m = m0 + mb + mi * 16 + l4 * 4 + j;
          int n = n0 + nb + ni * 16 + l15;
          Cout[(size_t)m * N + n] = acc[mi][ni][j];
        }
  } else {
    // RoPE epilogue. e in [0,6144): which = e>>11 (0=q,1=k,2=v), h=(e>>6)&31, d=e&63.
    // Wave spans 64 aligned cols => one head per wave; partner col d^32 lives in frag ni^2, same lane.
    #pragma unroll
    for (int ni = 0; ni < 4; ++ni){
      int e = n0 + nb + ni * 16 + l15;
      int which = e >> 11;
      int h = (e >> 6) & 31;
      int d = e & 63;
      unsigned short* dst = (which == 0) ? Qo : (which == 1) ? Ko : Vo;
      #pragma unroll
      for (int mi = 0; mi < 4; ++mi)
        #pragma unroll
        for (int j = 0; j < 4; ++j){
          int m = m0 + mb + mi * 16 + l4 * 4 + j;   // token index = b*2048 + l
          int b = m >> 11, l = m & 2047;
          float v = acc[mi][ni][j];
          float outv;
          if (which == 2){
            outv = v;
          } else {
            float pv = acc[mi][ni ^ 2][j];          // partner column d^32
            size_t ci = (size_t)(b * 2048 + l) * 64 + d;
            outv = v * cosp[ci] + ((d < 32) ? -pv : pv) * sinp[ci];
            if (which == 0) outv *= 0.125f;         // fold 1/sqrt(64)
          }
          dst[(size_t)((b * 32 + h) * 2048 + l) * 64 + d] = f2b(outv);
        }
    }
  }
}

// ---------------- V [BH, L, 64] -> Vt [BH, 64, L] ----------------
__global__ __launch_bounds__(256) void transpose_v(const unsigned short* __restrict__ V,
                                                   unsigned short* __restrict__ Vt){
  __shared__ unsigned short tile[64][72];
  int bh = blockIdx.x >> 5;
  int l0 = (blockIdx.x & 31) * 64;
  int t = threadIdx.x;
  #pragma unroll
  for (int i = 0; i < 2; ++i){
    int c = i * 256 + t;
    int row = c >> 3, ch = c & 7;
    uint4 v = *(const uint4*)(V + ((size_t)bh * 2048 + l0 + row) * 64 + ch * 8);
    const unsigned short* p = (const unsigned short*)&v;
    #pragma unroll
    for (int k = 0; k < 8; ++k) tile[row][ch * 8 + k] = p[k];
  }
  __syncthreads();
  #pragma unroll
  for (int i = 0; i < 2; ++i){
    int c = i * 256 + t;
    int drow = c >> 3, ch = c & 7;
    unsigned short tmp[8];
    #pragma unroll
    for (int k = 0; k < 8; ++k) tmp[k] = tile[ch * 8 + k][drow];
    *(uint4*)(Vt + ((size_t)bh * 64 + drow) * 2048 + l0 + ch * 8) = *(const uint4*)tmp;
  }
}

// ---------------- flash attention (causal) ----------------
// R1 per-wave structure (no inter-wave coupling) with:
//  * in-wave qtile pairing (qt, 15-qt): every wave has identical total work
//    -> perfect load balance regardless of dispatch order. Grid 64bh x 8 pairs.
//  * no-max softmax: exp(s) directly (|s| < ~40 << 88, f32-safe; softmax is
//    shift-invariant), per-lane partial row sums in registers, single
//    cross-lane reduce AFTER the k-loop. No cross-lane ops inside the loop.
__global__ __launch_bounds__(256, 2) void attn_fwd(
    const unsigned short* __restrict__ Q, const unsigned short* __restrict__ K,
    const unsigned short* __restrict__ Vt, unsigned short* __restrict__ Y)
{
  __shared__ __align__(16) unsigned char plds[4][4096];  // per-wave P tile [32][64] bf16, swizzled
  int idx = blockIdx.x;
  int bh = idx >> 3;                  // 8 blocks per bh, contiguous (L2 locality)
  int pr = idx & 7;                   // pair index: handles qtiles pr and 15-pr
  int b = bh >> 5, h = bh & 31;
  int t = threadIdx.x, wid = t >> 6, lane = t & 63;
  int l15 = lane & 15, l4 = lane >> 4;
  const unsigned short* Qb = Q  + (size_t)bh * 2048 * 64;
  const unsigned short* Kb = K  + (size_t)bh * 2048 * 64;
  const unsigned short* Vb = Vt + (size_t)bh * 64 * 2048;
  unsigned char* myp = plds[wid];

  for (int half = 0; half < 2; ++half){
    int qt = half ? (15 - pr) : pr;
    int q0 = qt * 128 + wid * 32;     // 32 q-rows per wave

    bf16x8 aq[2][2];
    #pragma unroll
    for (int mi = 0; mi < 2; ++mi)
      #pragma unroll
      for (int ks = 0; ks < 2; ++ks)
        aq[mi][ks] = *(const bf16x8*)(Qb + (size_t)(q0 + mi * 16 + l15) * 64 + ks * 32 + l4 * 8);

    f32x4 acc[2][4];
    float ps[2][4];
    #pragma unroll
    for (int mi = 0; mi < 2; ++mi){
      #pragma unroll
      for (int nd = 0; nd < 4; ++nd) acc[mi][nd] = (f32x4){0.f, 0.f, 0.f, 0.f};
      #pragma unroll
      for (int j = 0; j < 4; ++j) ps[mi][j] = 0.f;
    }

    int nkt = ((q0 + 31) >> 6) + 1;
    for (int kt = 0; kt < nkt; ++kt){
      int kv0 = kt * 64;
      // ---- K fragment loads (8 x b128, independent) ----
      bf16x8 bk[2][4];
      #pragma unroll
      for (int ks = 0; ks < 2; ++ks)
        #pragma unroll
        for (int ni = 0; ni < 4; ++ni)
          bk[ks][ni] = *(const bf16x8*)(Kb + (size_t)(kv0 + ni * 16 + l15) * 64 + ks * 32 + l4 * 8);
      // ---- QK^T ----
      f32x4 s[2][4];
      #pragma unroll
      for (int mi = 0; mi < 2; ++mi)
        #pragma unroll
        for (int ni = 0; ni < 4; ++ni)
          s[mi][ni] = (f32x4){0.f, 0.f, 0.f, 0.f};
      #pragma unroll
      for (int ks = 0; ks < 2; ++ks)
        #pragma unroll
        for (int mi = 0; mi < 2; ++mi)
          #pragma unroll
          for (int ni = 0; ni < 4; ++ni)
            s[mi][ni] = __builtin_amdgcn_mfma_f32_16x16x32_bf16(aq[mi][ks], bk[ks][ni], s[mi][ni], 0, 0, 0);
      // ---- causal mask (diagonal tile only) ----
      if (kt == nkt - 1){
        #pragma unroll
        for (int mi = 0; mi < 2; ++mi)
          #pragma unroll
          for (int ni = 0; ni < 4; ++ni)
            #pragma unroll
            for (int j = 0; j < 4; ++j){
              int kv = kv0 + ni * 16 + l15;
              int q  = q0 + mi * 16 + l4 * 4 + j;
              if (kv > q) s[mi][ni][j] = -1e30f;
            }
      }
      // ---- exp + per-lane partial row sums (no cross-lane ops) ----
      #pragma unroll
      for (int mi = 0; mi < 2; ++mi)
        #pragma unroll
        for (int ni = 0; ni < 4; ++ni)
          #pragma unroll
          for (int j = 0; j < 4; ++j){
            float p = __expf(s[mi][ni][j]);
            s[mi][ni][j] = p;
            ps[mi][j] += p;
          }
      // ---- P (C-layout) -> per-wave LDS (swizzled), packed bf16 pairs ----
      #pragma unroll
      for (int mi = 0; mi < 2; ++mi)
        #pragma unroll
        for (int j = 0; j < 4; ++j){
          int r = mi * 16 + l4 * 4 + j;
          int sw = (r & 7) << 4;
          unsigned char* rowp = myp + r * 128;
          #pragma unroll
          for (int p2 = 0; p2 < 2; ++p2){
            unsigned int pk;
            asm("v_cvt_pk_bf16_f32 %0, %1, %2" : "=v"(pk) : "v"(s[mi][2 * p2][j]), "v"(s[mi][2 * p2 + 1][j]));
            *(unsigned short*)(rowp + ((p2 * 64      + 2 * l15) ^ sw)) = (unsigned short)pk;
            *(unsigned short*)(rowp + ((p2 * 64 + 32 + 2 * l15) ^ sw)) = (unsigned short)(pk >> 16);
          }
        }
      __threadfence_block();   // wave-local LDS write->read ordering
      // ---- PV ----
      #pragma unroll
      for (int ks2 = 0; ks2 < 2; ++ks2){
        bf16x8 ap[2], bv[4];
        #pragma unroll
        for (int mi = 0; mi < 2; ++mi){
          int r = mi * 16 + l15;
          ap[mi] = *(const bf16x8*)(myp + r * 128 + ((ks2 * 64 + l4 * 16) ^ ((r & 7) << 4)));
        }
        #pragma unroll
        for (int nd = 0; nd < 4; ++nd)
          bv[nd] = *(const bf16x8*)(Vb + (size_t)(nd * 16 + l15) * 2048 + kv0 + ks2 * 32 + l4 * 8);
        #pragma unroll
        for (int mi = 0; mi < 2; ++mi)
          #pragma unroll
          for (int nd = 0; nd < 4; ++nd)
            acc[mi][nd] = __builtin_amdgcn_mfma_f32_16x16x32_bf16(ap[mi], bv[nd], acc[mi][nd], 0, 0, 0);
      }
    }
    // ---- single cross-lane row-sum reduce (over the 16 l15 lanes) ----
    float lrow[2][4];
    #pragma unroll
    for (int mi = 0; mi < 2; ++mi)
      #pragma unroll
      for (int j = 0; j < 4; ++j){
        float v = ps[mi][j];
        v += SWZ(v, 0x041F);
        v += SWZ(v, 0x081F);
        v += SWZ(v, 0x101F);
        v += SWZ(v, 0x201F);
        lrow[mi][j] = v;
      }
    // ---- epilogue ----
    #pragma unroll
    for (int mi = 0; mi < 2; ++mi){
      float inv[4];
      #pragma unroll
      for (int j = 0; j < 4; ++j) inv[j] = 1.f / lrow[mi][j];
      #pragma unroll
      for (int nd = 0; nd < 4; ++nd)
        #pragma unroll
        for (int j = 0; j < 4; ++j){
          int q = q0 + mi * 16 + l4 * 4 + j;
          int d = nd * 16 + l15;
          Y[(size_t)(b * 2048 + q) * 2048 + h * 64 + d] = f2b(acc[mi][nd][j] * inv[j]);
        }
    }
  }
}

// ---------------- launch ----------------
extern "C" void kernel_launch(void* const* d_in, const int* in_sizes, int n_in,
                              void* d_out, int out_size, void* d_ws, size_t ws_size,
                              hipStream_t stream){
  (void)in_sizes; (void)n_in; (void)out_size; (void)ws_size;
  const float* x     = (const float*)d_in[0];
  const float* cosp  = (const float*)d_in[1];
  const float* sinp  = (const float*)d_in[2];
  const float* Wqkv  = (const float*)d_in[3];
  const float* Wproj = (const float*)d_in[4];
  float* out = (float*)d_out;
  char* ws = (char*)d_ws;

  // workspace layout (96 MiB, with aliasing):
  // [0,16M)   Xb  (bf16 x)            -> reused as Vt after GEMM1
  // [16,40M)  Wqkvb
  // [40,48M)  Wprojb
  // [48,64M)  Q   [64,80M) K   [80,96M) V -> reused as Y after transpose
  unsigned short* Xb  = (unsigned short*)(ws);
  unsigned short* Wqb = (unsigned short*)(ws + 16777216);
  unsigned short* Wpb = (unsigned short*)(ws + 41943040);
  unsigned short* Qb  = (unsigned short*)(ws + 50331648);
  unsigned short* Kb  = (unsigned short*)(ws + 67108864);
  unsigned short* Vb  = (unsigned short*)(ws + 83886080);
  unsigned short* Vtb = Xb;   // alias: Xb dead after GEMM1
  unsigned short* Yb  = Vb;   // alias: V dead after transpose

  cvt_f32_bf16<<<1536, 256, 0, stream>>>(x,     Xb,  2097152);  // 8.39M elems
  cvt_f32_bf16<<<1536, 256, 0, stream>>>(Wqkv,  Wqb, 3145728);  // 12.58M
  cvt_f32_bf16<<<1536, 256, 0, stream>>>(Wproj, Wpb, 1048576);  // 4.19M

  // QKV GEMM + RoPE: M=4096, N=6144, K=2048
  gemm_bt<0><<<32 * 48, 256, 0, stream>>>(Xb, Wqb, 2048, 48, 6144,
                                          cosp, sinp, Qb, Kb, Vb, nullptr);
  transpose_v<<<2048, 256, 0, stream>>>(Vb, Vtb);
  attn_fwd<<<512, 256, 0, stream>>>(Qb, Kb, Vtb, Yb);
  // out proj: M=4096, N=2048, K=2048, f32 out
  gemm_bt<1><<<32 * 16, 256, 0, stream>>>(Yb, Wpb, 2048, 16, 2048,
                                          nullptr, nullptr, nullptr, nullptr, nullptr, out);
}

// Round 5
// 333.565 us; speedup vs baseline: 1.9896x; 1.0277x over previous
//
#include <hip/hip_runtime.h>
#include <stdint.h>

#define DEV static __device__ __forceinline__

typedef __attribute__((ext_vector_type(8))) short bf16x8;
typedef __attribute__((ext_vector_type(4))) float f32x4;

DEV unsigned short f2b(float f){
  union { float f; unsigned int u; } v; v.f = f;
  return (unsigned short)((v.u + 0x7FFFu + ((v.u >> 16) & 1u)) >> 16);
}

#define SWZ(v, pat) __int_as_float(__builtin_amdgcn_ds_swizzle(__float_as_int(v), pat))

// async global->LDS, 16B per lane; dest = wave-uniform base + lane*16 (linear).
// Swizzled layout achieved by pre-swizzling the per-lane global source address.
#define GLD16(g, l) __builtin_amdgcn_global_load_lds(                         \
    (const __attribute__((address_space(1))) void*)(g),                       \
    (__attribute__((address_space(3))) void*)(l), 16, 0, 0)

// ---------------- f32 -> bf16 convert ----------------
__global__ __launch_bounds__(256) void cvt_f32_bf16(const float* __restrict__ in,
                                                    unsigned short* __restrict__ out, int n4){
  int stride = gridDim.x * blockDim.x;
  for (int i = blockIdx.x * blockDim.x + threadIdx.x; i < n4; i += stride){
    float4 v = ((const float4*)in)[i];
    ushort4 o = make_ushort4(f2b(v.x), f2b(v.y), f2b(v.z), f2b(v.w));
    ((ushort4*)out)[i] = o;
  }
}

// ---------------- bt-GEMM: C[M,N] = A[M,K] * B[N,K]^T, 128x128 tile ----------------
// Staging via global_load_lds (async DMA, no VGPR round-trip). LDS layout is the
// same swizzled one as before: lds[row*128 + (ch*16 ^ ((row&7)<<4))] = X[row][ch].
// For linear dest o = base + 16*lane: row = rb + i*8 + (lane>>3), ch = (lane&7)^(lane>>3).
// MODE 0: QKV gemm, fused RoPE epilogue -> Q,K,V [B,H,L,HD] bf16 (Q pre-scaled 1/8)
// MODE 1: proj gemm, f32 output [M,N]
template<int MODE>
__global__ __launch_bounds__(256, 2) void gemm_bt(
    const unsigned short* __restrict__ A,
    const unsigned short* __restrict__ Bw,
    int K, int nbn, int N,
    const float* __restrict__ cosp, const float* __restrict__ sinp,
    unsigned short* __restrict__ Qo, unsigned short* __restrict__ Ko,
    unsigned short* __restrict__ Vo, float* __restrict__ Cout)
{
  __shared__ __align__(16) unsigned char lds[32768]; // A tile @0 (16KB), B tile @16384
  const int t = threadIdx.x;
  const int wid = t >> 6, lane = t & 63;
  const int l15 = lane & 15, l4 = lane >> 4;
  const int bm = blockIdx.x / nbn, bn = blockIdx.x % nbn;
  const int m0 = bm * 128, n0 = bn * 128;
  const int mb = (wid >> 1) * 64, nb = (wid & 1) * 64;

  // staging source map (pre-swizzled): wave wid covers rows [wid*32, wid*32+32)
  const int rsub = lane >> 3;               // 0..7
  const int sch  = (lane & 7) ^ rsub;       // swizzled 16B-chunk index

  f32x4 acc[4][4];
  #pragma unroll
  for (int i = 0; i < 4; ++i)
    #pragma unroll
    for (int j = 0; j < 4; ++j)
      acc[i][j] = (f32x4){0.f, 0.f, 0.f, 0.f};

  for (int k0 = 0; k0 < K; k0 += 64){
    __syncthreads();
    #pragma unroll
    for (int i = 0; i < 4; ++i){
      int row = wid * 32 + i * 8 + rsub;
      GLD16(A  + (size_t)(m0 + row) * K + k0 + sch * 8, lds + wid * 4096 + i * 1024);
      GLD16(Bw + (size_t)(n0 + row) * K + k0 + sch * 8, lds + 16384 + wid * 4096 + i * 1024);
    }
    __syncthreads();   // compiler drains vmcnt(0) before barrier -> tile ready
    #pragma unroll
    for (int ks = 0; ks < 2; ++ks){
      bf16x8 af[4], bfr[4];
      #pragma unroll
      for (int mi = 0; mi < 4; ++mi){
        int r = mb + mi * 16 + l15, ch = ks * 4 + l4;
        af[mi] = *(const bf16x8*)(lds + r * 128 + ((ch * 16) ^ ((r & 7) << 4)));
      }
      #pragma unroll
      for (int ni = 0; ni < 4; ++ni){
        int r = nb + ni * 16 + l15, ch = ks * 4 + l4;
        bfr[ni] = *(const bf16x8*)(lds + 16384 + r * 128 + ((ch * 16) ^ ((r & 7) << 4)));
      }
      #pragma unroll
      for (int mi = 0; mi < 4; ++mi)
        #pragma unroll
        for (int ni = 0; ni < 4; ++ni)
          acc[mi][ni] = __builtin_amdgcn_mfma_f32_16x16x32_bf16(af[mi], bfr[ni], acc[mi][ni], 0, 0, 0);
    }
  }

  if (MODE == 1){
    #pragma unroll
    for (int mi = 0; mi < 4; ++mi)
      #pragma unroll
      for (int ni = 0; ni < 4; ++ni)
        #pragma unroll
        for (int j = 0; j < 4; ++j){
          int m = m0 + mb + mi * 16 + l4 * 4 + j;
          int n = n0 + nb + ni * 16 + l15;
          Cout[(size_t)m * N + n] = acc[mi][ni][j];
        }
  } else {
    // RoPE epilogue. e in [0,6144): which = e>>11 (0=q,1=k,2=v), h=(e>>6)&31, d=e&63.
    // Wave spans 64 aligned cols => one head per wave; partner col d^32 lives in frag ni^2, same lane.
    #pragma unroll
    for (int ni = 0; ni < 4; ++ni){
      int e = n0 + nb + ni * 16 + l15;
      int which = e >> 11;
      int h = (e >> 6) & 31;
      int d = e & 63;
      unsigned short* dst = (which == 0) ? Qo : (which == 1) ? Ko : Vo;
      #pragma unroll
      for (int mi = 0; mi < 4; ++mi)
        #pragma unroll
        for (int j = 0; j < 4; ++j){
          int m = m0 + mb + mi * 16 + l4 * 4 + j;   // token index = b*2048 + l
          int b = m >> 11, l = m & 2047;
          float v = acc[mi][ni][j];
          float outv;
          if (which == 2){
            outv = v;
          } else {
            float pv = acc[mi][ni ^ 2][j];          // partner column d^32
            size_t ci = (size_t)(b * 2048 + l) * 64 + d;
            outv = v * cosp[ci] + ((d < 32) ? -pv : pv) * sinp[ci];
            if (which == 0) outv *= 0.125f;         // fold 1/sqrt(64)
          }
          dst[(size_t)((b * 32 + h) * 2048 + l) * 64 + d] = f2b(outv);
        }
    }
  }
}

// ---------------- V [BH, L, 64] -> Vt [BH, 64, L] ----------------
__global__ __launch_bounds__(256) void transpose_v(const unsigned short* __restrict__ V,
                                                   unsigned short* __restrict__ Vt){
  __shared__ unsigned short tile[64][72];
  int bh = blockIdx.x >> 5;
  int l0 = (blockIdx.x & 31) * 64;
  int t = threadIdx.x;
  #pragma unroll
  for (int i = 0; i < 2; ++i){
    int c = i * 256 + t;
    int row = c >> 3, ch = c & 7;
    uint4 v = *(const uint4*)(V + ((size_t)bh * 2048 + l0 + row) * 64 + ch * 8);
    const unsigned short* p = (const unsigned short*)&v;
    #pragma unroll
    for (int k = 0; k < 8; ++k) tile[row][ch * 8 + k] = p[k];
  }
  __syncthreads();
  #pragma unroll
  for (int i = 0; i < 2; ++i){
    int c = i * 256 + t;
    int drow = c >> 3, ch = c & 7;
    unsigned short tmp[8];
    #pragma unroll
    for (int k = 0; k < 8; ++k) tmp[k] = tile[ch * 8 + k][drow];
    *(uint4*)(Vt + ((size_t)bh * 64 + drow) * 2048 + l0 + ch * 8) = *(const uint4*)tmp;
  }
}

// ---------------- flash attention (causal) ----------------
// Per-wave independent tiles; in-wave qtile pairing (qt, 15-qt) -> identical
// total work per wave regardless of dispatch order. No-max softmax (scores
// bounded; softmax shift-invariant), single cross-lane reduce after k-loop.
__global__ __launch_bounds__(256, 2) void attn_fwd(
    const unsigned short* __restrict__ Q, const unsigned short* __restrict__ K,
    const unsigned short* __restrict__ Vt, unsigned short* __restrict__ Y)
{
  __shared__ __align__(16) unsigned char plds[4][4096];  // per-wave P tile [32][64] bf16, swizzled
  int idx = blockIdx.x;
  int bh = idx >> 3;                  // 8 blocks per bh, contiguous (L2 locality)
  int pr = idx & 7;                   // pair index: handles qtiles pr and 15-pr
  int b = bh >> 5, h = bh & 31;
  int t = threadIdx.x, wid = t >> 6, lane = t & 63;
  int l15 = lane & 15, l4 = lane >> 4;
  const unsigned short* Qb = Q  + (size_t)bh * 2048 * 64;
  const unsigned short* Kb = K  + (size_t)bh * 2048 * 64;
  const unsigned short* Vb = Vt + (size_t)bh * 64 * 2048;
  unsigned char* myp = plds[wid];

  for (int half = 0; half < 2; ++half){
    int qt = half ? (15 - pr) : pr;
    int q0 = qt * 128 + wid * 32;     // 32 q-rows per wave

    bf16x8 aq[2][2];
    #pragma unroll
    for (int mi = 0; mi < 2; ++mi)
      #pragma unroll
      for (int ks = 0; ks < 2; ++ks)
        aq[mi][ks] = *(const bf16x8*)(Qb + (size_t)(q0 + mi * 16 + l15) * 64 + ks * 32 + l4 * 8);

    f32x4 acc[2][4];
    float ps[2][4];
    #pragma unroll
    for (int mi = 0; mi < 2; ++mi){
      #pragma unroll
      for (int nd = 0; nd < 4; ++nd) acc[mi][nd] = (f32x4){0.f, 0.f, 0.f, 0.f};
      #pragma unroll
      for (int j = 0; j < 4; ++j) ps[mi][j] = 0.f;
    }

    int nkt = ((q0 + 31) >> 6) + 1;
    for (int kt = 0; kt < nkt; ++kt){
      int kv0 = kt * 64;
      // ---- K fragment loads (8 x b128, independent) ----
      bf16x8 bk[2][4];
      #pragma unroll
      for (int ks = 0; ks < 2; ++ks)
        #pragma unroll
        for (int ni = 0; ni < 4; ++ni)
          bk[ks][ni] = *(const bf16x8*)(Kb + (size_t)(kv0 + ni * 16 + l15) * 64 + ks * 32 + l4 * 8);
      // ---- QK^T ----
      f32x4 s[2][4];
      #pragma unroll
      for (int mi = 0; mi < 2; ++mi)
        #pragma unroll
        for (int ni = 0; ni < 4; ++ni)
          s[mi][ni] = (f32x4){0.f, 0.f, 0.f, 0.f};
      #pragma unroll
      for (int ks = 0; ks < 2; ++ks)
        #pragma unroll
        for (int mi = 0; mi < 2; ++mi)
          #pragma unroll
          for (int ni = 0; ni < 4; ++ni)
            s[mi][ni] = __builtin_amdgcn_mfma_f32_16x16x32_bf16(aq[mi][ks], bk[ks][ni], s[mi][ni], 0, 0, 0);
      // ---- causal mask (diagonal tile only) ----
      if (kt == nkt - 1){
        #pragma unroll
        for (int mi = 0; mi < 2; ++mi)
          #pragma unroll
          for (int ni = 0; ni < 4; ++ni)
            #pragma unroll
            for (int j = 0; j < 4; ++j){
              int kv = kv0 + ni * 16 + l15;
              int q  = q0 + mi * 16 + l4 * 4 + j;
              if (kv > q) s[mi][ni][j] = -1e30f;
            }
      }
      // ---- exp + per-lane partial row sums (no cross-lane ops) ----
      #pragma unroll
      for (int mi = 0; mi < 2; ++mi)
        #pragma unroll
        for (int ni = 0; ni < 4; ++ni)
          #pragma unroll
          for (int j = 0; j < 4; ++j){
            float p = __expf(s[mi][ni][j]);
            s[mi][ni][j] = p;
            ps[mi][j] += p;
          }
      // ---- P (C-layout) -> per-wave LDS (swizzled), packed bf16 pairs ----
      #pragma unroll
      for (int mi = 0; mi < 2; ++mi)
        #pragma unroll
        for (int j = 0; j < 4; ++j){
          int r = mi * 16 + l4 * 4 + j;
          int sw = (r & 7) << 4;
          unsigned char* rowp = myp + r * 128;
          #pragma unroll
          for (int p2 = 0; p2 < 2; ++p2){
            unsigned int pk;
            asm("v_cvt_pk_bf16_f32 %0, %1, %2" : "=v"(pk) : "v"(s[mi][2 * p2][j]), "v"(s[mi][2 * p2 + 1][j]));
            *(unsigned short*)(rowp + ((p2 * 64      + 2 * l15) ^ sw)) = (unsigned short)pk;
            *(unsigned short*)(rowp + ((p2 * 64 + 32 + 2 * l15) ^ sw)) = (unsigned short)(pk >> 16);
          }
        }
    __threadfence_block();   // wave-local LDS write->read ordering
      // ---- PV ----
      #pragma unroll
      for (int ks2 = 0; ks2 < 2; ++ks2){
        bf16x8 ap[2], bv[4];
        #pragma unroll
        for (int mi = 0; mi < 2; ++mi){
          int r = mi * 16 + l15;
          ap[mi] = *(const bf16x8*)(myp + r * 128 + ((ks2 * 64 + l4 * 16) ^ ((r & 7) << 4)));
        }
        #pragma unroll
        for (int nd = 0; nd < 4; ++nd)
          bv[nd] = *(const bf16x8*)(Vb + (size_t)(nd * 16 + l15) * 2048 + kv0 + ks2 * 32 + l4 * 8);
        #pragma unroll
        for (int mi = 0; mi < 2; ++mi)
          #pragma unroll
          for (int nd = 0; nd < 4; ++nd)
            acc[mi][nd] = __builtin_amdgcn_mfma_f32_16x16x32_bf16(ap[mi], bv[nd], acc[mi][nd], 0, 0, 0);
      }
    }
    // ---- single cross-lane row-sum reduce (over the 16 l15 lanes) ----
    float lrow[2][4];
    #pragma unroll
    for (int mi = 0; mi < 2; ++mi)
      #pragma unroll
      for (int j = 0; j < 4; ++j){
        float v = ps[mi][j];
        v += SWZ(v, 0x041F);
        v += SWZ(v, 0x081F);
        v += SWZ(v, 0x101F);
        v += SWZ(v, 0x201F);
        lrow[mi][j] = v;
      }
    // ---- epilogue ----
    #pragma unroll
    for (int mi = 0; mi < 2; ++mi){
      float inv[4];
      #pragma unroll
      for (int j = 0; j < 4; ++j) inv[j] = 1.f / lrow[mi][j];
      #pragma unroll
      for (int nd = 0; nd < 4; ++nd)
        #pragma unroll
        for (int j = 0; j < 4; ++j){
          int q = q0 + mi * 16 + l4 * 4 + j;
          int d = nd * 16 + l15;
          Y[(size_t)(b * 2048 + q) * 2048 + h * 64 + d] = f2b(acc[mi][nd][j] * inv[j]);
        }
    }
  }
}

// ---------------- launch ----------------
extern "C" void kernel_launch(void* const* d_in, const int* in_sizes, int n_in,
                              void* d_out, int out_size, void* d_ws, size_t ws_size,
                              hipStream_t stream){
  (void)in_sizes; (void)n_in; (void)out_size; (void)ws_size;
  const float* x     = (const float*)d_in[0];
  const float* cosp  = (const float*)d_in[1];
  const float* sinp  = (const float*)d_in[2];
  const float* Wqkv  = (const float*)d_in[3];
  const float* Wproj = (const float*)d_in[4];
  float* out = (float*)d_out;
  char* ws = (char*)d_ws;

  // workspace layout (96 MiB, with aliasing):
  // [0,16M)   Xb  (bf16 x)            -> reused as Vt after GEMM1
  // [16,40M)  Wqkvb
  // [40,48M)  Wprojb
  // [48,64M)  Q   [64,80M) K   [80,96M) V -> reused as Y after transpose
  unsigned short* Xb  = (unsigned short*)(ws);
  unsigned short* Wqb = (unsigned short*)(ws + 16777216);
  unsigned short* Wpb = (unsigned short*)(ws + 41943040);
  unsigned short* Qb  = (unsigned short*)(ws + 50331648);
  unsigned short* Kb  = (unsigned short*)(ws + 67108864);
  unsigned short* Vb  = (unsigned short*)(ws + 83886080);
  unsigned short* Vtb = Xb;   // alias: Xb dead after GEMM1
  unsigned short* Yb  = Vb;   // alias: V dead after transpose

  cvt_f32_bf16<<<1536, 256, 0, stream>>>(x,     Xb,  2097152);  // 8.39M elems
  cvt_f32_bf16<<<1536, 256, 0, stream>>>(Wqkv,  Wqb, 3145728);  // 12.58M
  cvt_f32_bf16<<<1536, 256, 0, stream>>>(Wproj, Wpb, 1048576);  // 4.19M

  // QKV GEMM + RoPE: M=4096, N=6144, K=2048
  gemm_bt<0><<<32 * 48, 256, 0, stream>>>(Xb, Wqb, 2048, 48, 6144,
                                          cosp, sinp, Qb, Kb, Vb, nullptr);
  transpose_v<<<2048, 256, 0, stream>>>(Vb, Vtb);
  attn_fwd<<<512, 256, 0, stream>>>(Qb, Kb, Vtb, Yb);
  // out proj: M=4096, N=2048, K=2048, f32 out
  gemm_bt<1><<<32 * 16, 256, 0, stream>>>(Yb, Wpb, 2048, 16, 2048,
                                          nullptr, nullptr, nullptr, nullptr, nullptr, out);
}

// Round 6
// 330.261 us; speedup vs baseline: 2.0095x; 1.0100x over previous
//
#include <hip/hip_runtime.h>
#include <stdint.h>

#define DEV static __device__ __forceinline__

typedef __attribute__((ext_vector_type(8))) short bf16x8;
typedef __attribute__((ext_vector_type(4))) float f32x4;

DEV unsigned short f2b(float f){
  union { float f; unsigned int u; } v; v.f = f;
  return (unsigned short)((v.u + 0x7FFFu + ((v.u >> 16) & 1u)) >> 16);
}

#define SWZ(v, pat) __int_as_float(__builtin_amdgcn_ds_swizzle(__float_as_int(v), pat))

// async global->LDS, 16B per lane; dest = wave-uniform base + lane*16 (linear).
// Swizzled layout achieved by pre-swizzling the per-lane global source address.
#define GLD16(g, l) __builtin_amdgcn_global_load_lds(                         \
    (const __attribute__((address_space(1))) void*)(g),                       \
    (__attribute__((address_space(3))) void*)(l), 16, 0, 0)

// ---------------- f32 -> bf16 convert ----------------
__global__ __launch_bounds__(256) void cvt_f32_bf16(const float* __restrict__ in,
                                                    unsigned short* __restrict__ out, int n4){
  int stride = gridDim.x * blockDim.x;
  for (int i = blockIdx.x * blockDim.x + threadIdx.x; i < n4; i += stride){
    float4 v = ((const float4*)in)[i];
    ushort4 o = make_ushort4(f2b(v.x), f2b(v.y), f2b(v.z), f2b(v.w));
    ((ushort4*)out)[i] = o;
  }
}

// ---------------- ring-buffered bt-GEMM: C[M,N] = A[M,2048] * B[N,2048]^T ----------------
// BM=256, BN=NI*64, BK=64, 8 waves (2Mx4N, 512thr), per-wave out 128 x NI*16.
// Double-buffered LDS; per K-tile: stage next tile (7 async gloads/wave) -> counted
// s_waitcnt vmcnt(NLD) (never 0 in main loop) -> raw s_barrier -> ds_read+MFMA -> raw
// s_barrier. Raw barriers keep prefetch in flight (no __syncthreads vmcnt(0) drain).
// MODE 0: fused RoPE epilogue -> Q,K,V [B,H,L,HD] bf16 (Q pre-scaled 1/8).
//   Wqkv N-dim is consumed in PERMUTED order: virtual col 2j -> phys d=j, 2j+1 -> d=j+32,
//   so each RoPE partner pair sits in adjacent lanes -> one ds_swizzle(lane^1) per elem.
// MODE 1: plain f32 output [M,N].
template<int NI, int MODE>
__global__ __launch_bounds__(512, 2) void gemm_ring(
    const unsigned short* __restrict__ A,
    const unsigned short* __restrict__ Bw,
    int nbn,
    const float* __restrict__ cosp, const float* __restrict__ sinp,
    unsigned short* __restrict__ Qo, unsigned short* __restrict__ Ko,
    unsigned short* __restrict__ Vo, float* __restrict__ Cout, int N)
{
  constexpr int BN  = NI * 64;
  constexpr int ASZ = 256 * 128;           // 32KB A region per buffer
  constexpr int BSZ = BN * 128;            // B region
  constexpr int BUF = ASZ + BSZ;
  __shared__ __align__(16) unsigned char lds[2 * BUF];

  const int t = threadIdx.x;
  const int wid = t >> 6, lane = t & 63;
  const int l15 = lane & 15, l4 = lane >> 4;
  const int wr = wid >> 2, wc = wid & 3;   // wave grid 2M x 4N

  // XCD-aware block swizzle (grid is a multiple of 8)
  const int cpx = gridDim.x >> 3;
  const int bid = (blockIdx.x & 7) * cpx + (blockIdx.x >> 3);
  const int bm = bid / nbn, bn = bid % nbn;
  const int m0 = bm * 256, n0 = bn * BN;

  // staging map: per issue, wave covers 8 rows x 8 chunks(16B); linear LDS dest,
  // pre-swizzled global chunk index sch = (lane&7) ^ (row&7), row&7 = lane>>3.
  const int rsub = lane >> 3;
  const int sch  = (lane & 7) ^ rsub;

  auto stage = [&](int kt, int ib) {
    const unsigned short* As = A + (size_t)(m0 + wid * 32 + rsub) * 2048 + kt * 64 + sch * 8;
    unsigned char* ldsA = lds + ib * BUF + wid * 4096;
    #pragma unroll
    for (int i = 0; i < 4; ++i)
      GLD16(As + (size_t)i * 8 * 2048, ldsA + i * 1024);
    unsigned char* ldsB = lds + ib * BUF + ASZ + wid * (BN * 16);
    #pragma unroll
    for (int i = 0; i < NI; ++i){
      int rv = n0 + wid * (BN / 8) + i * 8 + rsub;
      int rp = (MODE == 0) ? ((rv & ~63) | ((rv & 63) >> 1) | ((rv & 1) << 5)) : rv;
      GLD16(Bw + (size_t)rp * 2048 + kt * 64 + sch * 8, ldsB + i * 1024);
    }
  };

  f32x4 acc[8][NI];
  #pragma unroll
  for (int mi = 0; mi < 8; ++mi)
    #pragma unroll
    for (int ni = 0; ni < NI; ++ni)
      acc[mi][ni] = (f32x4){0.f, 0.f, 0.f, 0.f};

  auto compute = [&](int ib) {
    const unsigned char* Ab = lds + ib * BUF;
    const unsigned char* Bb = Ab + ASZ;
    bf16x8 af[2][8], bfr[2][NI];
    #pragma unroll
    for (int ks = 0; ks < 2; ++ks){
      #pragma unroll
      for (int mi = 0; mi < 8; ++mi){
        int r = wr * 128 + mi * 16 + l15, ch = ks * 4 + l4;
        af[ks][mi] = *(const bf16x8*)(Ab + r * 128 + ((ch * 16) ^ ((r & 7) << 4)));
      }
      #pragma unroll
      for (int ni = 0; ni < NI; ++ni){
        int r = wc * (NI * 16) + ni * 16 + l15, ch = ks * 4 + l4;
        bfr[ks][ni] = *(const bf16x8*)(Bb + r * 128 + ((ch * 16) ^ ((r & 7) << 4)));
      }
    }
    #pragma unroll
    for (int ks = 0; ks < 2; ++ks)
      #pragma unroll
      for (int mi = 0; mi < 8; ++mi)
        #pragma unroll
        for (int ni = 0; ni < NI; ++ni)
          acc[mi][ni] = __builtin_amdgcn_mfma_f32_16x16x32_bf16(af[ks][mi], bfr[ks][ni], acc[mi][ni], 0, 0, 0);
  };

  // prologue: stage K-tile 0
  stage(0, 0);
  // main loop: 31 iterations with counted vmcnt; peel the last (drain) iteration
  #pragma unroll 1
  for (int kt = 0; kt < 31; ++kt){
    int ib = kt & 1;
    stage(kt + 1, ib ^ 1);
    if (NI == 3) asm volatile("s_waitcnt vmcnt(7)" ::: "memory");
    else         asm volatile("s_waitcnt vmcnt(6)" ::: "memory");
    __builtin_amdgcn_s_barrier();        // all waves' K(kt) loads landed
    asm volatile("" ::: "memory");
    compute(ib);
    asm volatile("" ::: "memory");
    __builtin_amdgcn_s_barrier();        // all reads of buf[ib] done -> next stage may overwrite
  }
  asm volatile("s_waitcnt vmcnt(0)" ::: "memory");
  __builtin_amdgcn_s_barrier();
  asm volatile("" ::: "memory");
  compute(1);                            // kt=31 lives in buf 1

  // ---------------- epilogue ----------------
  if (MODE == 1){
    #pragma unroll
    for (int mi = 0; mi < 8; ++mi)
      #pragma unroll
      for (int ni = 0; ni < NI; ++ni)
        #pragma unroll
        for (int j = 0; j < 4; ++j){
          int m = m0 + wr * 128 + mi * 16 + l4 * 4 + j;
          int n = n0 + wc * (NI * 16) + ni * 16 + l15;
          Cout[(size_t)m * N + n] = acc[mi][ni][j];
        }
  } else {
    #pragma unroll
    for (int ni = 0; ni < NI; ++ni){
      int e16 = n0 + wc * (NI * 16) + ni * 16;   // virtual col base of this frag
      int which = e16 >> 11;                     // 0=q 1=k 2=v (uniform per frag)
      int h = (e16 >> 6) & 31;                   // head (uniform per frag)
      unsigned short* dst = (which == 0) ? Qo : (which == 1) ? Ko : Vo;
      int p = (e16 + l15) & 63;                  // virtual in-head position
      int d = ((p >> 1) | ((p & 1) << 5));       // physical dim
      #pragma unroll
      for (int mi = 0; mi < 8; ++mi)
        #pragma unroll
        for (int j = 0; j < 4; ++j){
          int m = m0 + wr * 128 + mi * 16 + l4 * 4 + j;   // token = b*2048 + l
          int b = m >> 11, l = m & 2047;
          float val = acc[mi][ni][j];
          float par = SWZ(val, 0x041F);                   // partner = lane^1
          float outv;
          if (which == 2){
            outv = val;
          } else {
            size_t ci = (size_t)(b * 2048 + l) * 64 + d;
            outv = val * cosp[ci] + ((p & 1) ? par : -par) * sinp[ci];
            if (which == 0) outv *= 0.125f;               // fold 1/sqrt(64)
          }
          dst[(size_t)((b * 32 + h) * 2048 + l) * 64 + d] = f2b(outv);
        }
    }
  }
}

// ---------------- V [BH, L, 64] -> Vt [BH, 64, L] ----------------
__global__ __launch_bounds__(256) void transpose_v(const unsigned short* __restrict__ V,
                                                   unsigned short* __restrict__ Vt){
  __shared__ unsigned short tile[64][72];
  int bh = blockIdx.x >> 5;
  int l0 = (blockIdx.x & 31) * 64;
  int t = threadIdx.x;
  #pragma unroll
  for (int i = 0; i < 2; ++i){
    int c = i * 256 + t;
    int row = c >> 3, ch = c & 7;
    uint4 v = *(const uint4*)(V + ((size_t)bh * 2048 + l0 + row) * 64 + ch * 8);
    const unsigned short* p = (const unsigned short*)&v;
    #pragma unroll
    for (int k = 0; k < 8; ++k) tile[row][ch * 8 + k] = p[k];
  }
  __syncthreads();
  #pragma unroll
  for (int i = 0; i < 2; ++i){
    int c = i * 256 + t;
    int drow = c >> 3, ch = c & 7;
    unsigned short tmp[8];
    #pragma unroll
    for (int k = 0; k < 8; ++k) tmp[k] = tile[ch * 8 + k][drow];
    *(uint4*)(Vt + ((size_t)bh * 64 + drow) * 2048 + l0 + ch * 8) = *(const uint4*)tmp;
  }
}

// ---------------- flash attention (causal) ----------------
// Per-wave independent tiles; in-wave qtile pairing (qt, 15-qt) -> identical
// total work per wave regardless of dispatch order. No-max softmax (scores
// bounded; softmax shift-invariant), single cross-lane reduce after k-loop.
__global__ __launch_bounds__(256, 2) void attn_fwd(
    const unsigned short* __restrict__ Q, const unsigned short* __restrict__ K,
    const unsigned short* __restrict__ Vt, unsigned short* __restrict__ Y)
{
  __shared__ __align__(16) unsigned char plds[4][4096];  // per-wave P tile [32][64] bf16, swizzled
  int idx = blockIdx.x;
  int bh = idx >> 3;                  // 8 blocks per bh, contiguous (L2 locality)
  int pr = idx & 7;                   // pair index: handles qtiles pr and 15-pr
  int b = bh >> 5, h = bh & 31;
  int t = threadIdx.x, wid = t >> 6, lane = t & 63;
  int l15 = lane & 15, l4 = lane >> 4;
  const unsigned short* Qb = Q  + (size_t)bh * 2048 * 64;
  const unsigned short* Kb = K  + (size_t)bh * 2048 * 64;
  const unsigned short* Vb = Vt + (size_t)bh * 64 * 2048;
  unsigned char* myp = plds[wid];

  for (int half = 0; half < 2; ++half){
    int qt = half ? (15 - pr) : pr;
    int q0 = qt * 128 + wid * 32;     // 32 q-rows per wave

    bf16x8 aq[2][2];
    #pragma unroll
    for (int mi = 0; mi < 2; ++mi)
      #pragma unroll
      for (int ks = 0; ks < 2; ++ks)
        aq[mi][ks] = *(const bf16x8*)(Qb + (size_t)(q0 + mi * 16 + l15) * 64 + ks * 32 + l4 * 8);

    f32x4 acc[2][4];
    float ps[2][4];
    #pragma unroll
    for (int mi = 0; mi < 2; ++mi){
      #pragma unroll
      for (int nd = 0; nd < 4; ++nd) acc[mi][nd] = (f32x4){0.f, 0.f, 0.f, 0.f};
      #pragma unroll
      for (int j = 0; j < 4; ++j) ps[mi][j] = 0.f;
    }

    int nkt = ((q0 + 31) >> 6) + 1;
    for (int kt = 0; kt < nkt; ++kt){
      int kv0 = kt * 64;
      bf16x8 bk[2][4];
      #pragma unroll
      for (int ks = 0; ks < 2; ++ks)
        #pragma unroll
        for (int ni = 0; ni < 4; ++ni)
          bk[ks][ni] = *(const bf16x8*)(Kb + (size_t)(kv0 + ni * 16 + l15) * 64 + ks * 32 + l4 * 8);
      f32x4 s[2][4];
      #pragma unroll
      for (int mi = 0; mi < 2; ++mi)
        #pragma unroll
        for (int ni = 0; ni < 4; ++ni)
          s[mi][ni] = (f32x4){0.f, 0.f, 0.f, 0.f};
      #pragma unroll
      for (int ks = 0; ks < 2; ++ks)
        #pragma unroll
        for (int mi = 0; mi < 2; ++mi)
          #pragma unroll
          for (int ni = 0; ni < 4; ++ni)
            s[mi][ni] = __builtin_amdgcn_mfma_f32_16x16x32_bf16(aq[mi][ks], bk[ks][ni], s[mi][ni], 0, 0, 0);
      if (kt == nkt - 1){
        #pragma unroll
        for (int mi = 0; mi < 2; ++mi)
          #pragma unroll
          for (int ni = 0; ni < 4; ++ni)
            #pragma unroll
            for (int j = 0; j < 4; ++j){
              int kv = kv0 + ni * 16 + l15;
              int q  = q0 + mi * 16 + l4 * 4 + j;
              if (kv > q) s[mi][ni][j] = -1e30f;
            }
      }
      #pragma unroll
      for (int mi = 0; mi < 2; ++mi)
        #pragma unroll
        for (int ni = 0; ni < 4; ++ni)
          #pragma unroll
          for (int j = 0; j < 4; ++j){
            float p = __expf(s[mi][ni][j]);
            s[mi][ni][j] = p;
            ps[mi][j] += p;
          }
      #pragma unroll
      for (int mi = 0; mi < 2; ++mi)
        #pragma unroll
        for (int j = 0; j < 4; ++j){
          int r = mi * 16 + l4 * 4 + j;
          int sw = (r & 7) << 4;
          unsigned char* rowp = myp + r * 128;
          #pragma unroll
          for (int p2 = 0; p2 < 2; ++p2){
            unsigned int pk;
            asm("v_cvt_pk_bf16_f32 %0, %1, %2" : "=v"(pk) : "v"(s[mi][2 * p2][j]), "v"(s[mi][2 * p2 + 1][j]));
            *(unsigned short*)(rowp + ((p2 * 64      + 2 * l15) ^ sw)) = (unsigned short)pk;
            *(unsigned short*)(rowp + ((p2 * 64 + 32 + 2 * l15) ^ sw)) = (unsigned short)(pk >> 16);
          }
        }
    __threadfence_block();   // wave-local LDS write->read ordering
      #pragma unroll
      for (int ks2 = 0; ks2 < 2; ++ks2){
        bf16x8 ap[2], bv[4];
        #pragma unroll
        for (int mi = 0; mi < 2; ++mi){
          int r = mi * 16 + l15;
          ap[mi] = *(const bf16x8*)(myp + r * 128 + ((ks2 * 64 + l4 * 16) ^ ((r & 7) << 4)));
        }
        #pragma unroll
        for (int nd = 0; nd < 4; ++nd)
          bv[nd] = *(const bf16x8*)(Vb + (size_t)(nd * 16 + l15) * 2048 + kv0 + ks2 * 32 + l4 * 8);
        #pragma unroll
        for (int mi = 0; mi < 2; ++mi)
          #pragma unroll
          for (int nd = 0; nd < 4; ++nd)
            acc[mi][nd] = __builtin_amdgcn_mfma_f32_16x16x32_bf16(ap[mi], bv[nd], acc[mi][nd], 0, 0, 0);
      }
    }
    float lrow[2][4];
    #pragma unroll
    for (int mi = 0; mi < 2; ++mi)
      #pragma unroll
      for (int j = 0; j < 4; ++j){
        float v = ps[mi][j];
        v += SWZ(v, 0x041F);
        v += SWZ(v, 0x081F);
        v += SWZ(v, 0x101F);
        v += SWZ(v, 0x201F);
        lrow[mi][j] = v;
      }
    #pragma unroll
    for (int mi = 0; mi < 2; ++mi){
      float inv[4];
      #pragma unroll
      for (int j = 0; j < 4; ++j) inv[j] = 1.f / lrow[mi][j];
      #pragma unroll
      for (int nd = 0; nd < 4; ++nd)
        #pragma unroll
        for (int j = 0; j < 4; ++j){
          int q = q0 + mi * 16 + l4 * 4 + j;
          int d = nd * 16 + l15;
          Y[(size_t)(b * 2048 + q) * 2048 + h * 64 + d] = f2b(acc[mi][nd][j] * inv[j]);
        }
    }
  }
}

// ---------------- launch ----------------
extern "C" void kernel_launch(void* const* d_in, const int* in_sizes, int n_in,
                              void* d_out, int out_size, void* d_ws, size_t ws_size,
                              hipStream_t stream){
  (void)in_sizes; (void)n_in; (void)out_size; (void)ws_size;
  const float* x     = (const float*)d_in[0];
  const float* cosp  = (const float*)d_in[1];
  const float* sinp  = (const float*)d_in[2];
  const float* Wqkv  = (const float*)d_in[3];
  const float* Wproj = (const float*)d_in[4];
  float* out = (float*)d_out;
  char* ws = (char*)d_ws;

  unsigned short* Xb  = (unsigned short*)(ws);
  unsigned short* Wqb = (unsigned short*)(ws + 16777216);
  unsigned short* Wpb = (unsigned short*)(ws + 41943040);
  unsigned short* Qb  = (unsigned short*)(ws + 50331648);
  unsigned short* Kb  = (unsigned short*)(ws + 67108864);
  unsigned short* Vb  = (unsigned short*)(ws + 83886080);
  unsigned short* Vtb = Xb;   // alias: Xb dead after GEMM1
  unsigned short* Yb  = Vb;   // alias: V dead after transpose

  cvt_f32_bf16<<<1536, 256, 0, stream>>>(x,     Xb,  2097152);
  cvt_f32_bf16<<<1536, 256, 0, stream>>>(Wqkv,  Wqb, 3145728);
  cvt_f32_bf16<<<1536, 256, 0, stream>>>(Wproj, Wpb, 1048576);

  // QKV GEMM + RoPE: M=4096 (16 m-tiles), N=6144 (32 n-tiles of 192) -> 512 blocks = 2/CU exact
  gemm_ring<3, 0><<<512, 512, 0, stream>>>(Xb, Wqb, 32, cosp, sinp, Qb, Kb, Vb, nullptr, 0);
  transpose_v<<<2048, 256, 0, stream>>>(Vb, Vtb);
  attn_fwd<<<512, 256, 0, stream>>>(Qb, Kb, Vtb, Yb);
  // out proj: M=4096, N=2048 (16 n-tiles of 128) -> 256 blocks = 1/CU exact
  gemm_ring<2, 1><<<256, 512, 0, stream>>>(Yb, Wpb, 16, nullptr, nullptr, nullptr, nullptr, nullptr, out, 2048);
}

// Round 7
// 312.347 us; speedup vs baseline: 2.1248x; 1.0574x over previous
//
#include <hip/hip_runtime.h>
#include <stdint.h>

#define DEV static __device__ __forceinline__

typedef __attribute__((ext_vector_type(8))) short bf16x8;
typedef __attribute__((ext_vector_type(4))) float f32x4;

DEV unsigned short f2b(float f){
  union { float f; unsigned int u; } v; v.f = f;
  return (unsigned short)((v.u + 0x7FFFu + ((v.u >> 16) & 1u)) >> 16);
}

#define SWZ(v, pat) __int_as_float(__builtin_amdgcn_ds_swizzle(__float_as_int(v), pat))

// async global->LDS, 16B per lane; dest = wave-uniform base + lane*16 (linear).
// Swizzled layout achieved by pre-swizzling the per-lane global source address.
#define GLD16(g, l) __builtin_amdgcn_global_load_lds(                         \
    (const __attribute__((address_space(1))) void*)(g),                       \
    (__attribute__((address_space(3))) void*)(l), 16, 0, 0)

// ---------------- fused f32 -> bf16 convert (x, Wqkv, Wproj in one launch) ----------------
__global__ __launch_bounds__(256) void cvt_all(const float* __restrict__ a,
                                               const float* __restrict__ b,
                                               const float* __restrict__ c,
                                               unsigned short* __restrict__ oa,
                                               unsigned short* __restrict__ ob,
                                               unsigned short* __restrict__ oc){
  const int n1 = 2097152, n2 = 3145728, n3 = 1048576;   // float4 counts
  int stride = gridDim.x * blockDim.x;
  for (int i = blockIdx.x * blockDim.x + threadIdx.x; i < n1 + n2 + n3; i += stride){
    const float* src; unsigned short* dst; int k;
    if (i < n1)            { src = a; dst = oa; k = i; }
    else if (i < n1 + n2)  { src = b; dst = ob; k = i - n1; }
    else                   { src = c; dst = oc; k = i - n1 - n2; }
    float4 v = ((const float4*)src)[k];
    ((ushort4*)dst)[k] = make_ushort4(f2b(v.x), f2b(v.y), f2b(v.z), f2b(v.w));
  }
}

// ---------------- ring-3 bt-GEMM: C[M,N] = A[M,2048] * B[N,2048]^T ----------------
// BM=256, BN=128, BK=64, 8 waves (4M x 2N, 512 thr), per-wave 64x64 output.
// LDS ring of 3 buffers (48KB each: A 32KB + B 16KB). Per K-tile t (one group):
//   stage(t+2) -> buf[(t+2)%3]   (6 global_load_lds per wave)
//   s_waitcnt vmcnt(12)          (t+1,t+2 stay in flight; tile t guaranteed landed)
//   16 x ds_read_b128 fragments from buf[t%3], 32 x MFMA, one s_barrier.
// Ring construction => staged buffer was fully consumed in group t-1 (behind the
// barrier) -> no region-freeing analysis needed. Prefetch distance 2 groups
// (~1100cy) covers HBM latency; vmcnt never drains to 0 until the 2-tile tail.
// MODE 0: fused RoPE epilogue -> Q,K,V [B,H,L,HD] bf16 (Q pre-scaled 1/8).
//   Wqkv N-dim consumed PERMUTED: virtual col 2j -> phys d=j, 2j+1 -> d=j+32, so
//   RoPE partner = lane^1 (one ds_swizzle). Verified in R6 (absmax unchanged).
// MODE 1: plain f32 output [M,N].
template<int MODE>
__global__ __launch_bounds__(512, 2) void gemm_r3(
    const unsigned short* __restrict__ A,
    const unsigned short* __restrict__ Bw,
    int nbn,
    const float* __restrict__ cosp, const float* __restrict__ sinp,
    unsigned short* __restrict__ Qo, unsigned short* __restrict__ Ko,
    unsigned short* __restrict__ Vo, float* __restrict__ Cout, int N)
{
  constexpr int BUF = 49152;               // 32KB A + 16KB B
  __shared__ __align__(16) unsigned char lds[3 * BUF];

  const int t = threadIdx.x;
  const int wid = t >> 6, lane = t & 63;
  const int l15 = lane & 15, l4 = lane >> 4;
  const int wr = wid >> 1, wc = wid & 1;   // wave grid 4M x 2N

  // XCD-aware block swizzle (grids are multiples of 8)
  const int cpx = gridDim.x >> 3;
  const int bid = (blockIdx.x & 7) * cpx + (blockIdx.x >> 3);
  const int bm = bid / nbn, bn = bid % nbn;
  const int m0 = bm * 256, n0 = bn * 128;

  // staging source map: linear LDS dest (wave-uniform base + lane*16), global
  // chunk pre-swizzled: sch = (lane&7) ^ (row&7), row&7 = lane>>3.
  const int rsub = lane >> 3;
  const int sch  = (lane & 7) ^ rsub;

  auto stage = [&](int kt, int rb){
    unsigned char* base = lds + rb * BUF;
    // A: wave wid covers rows [wid*32, wid*32+32) as 4 x 8-row loads
    const unsigned short* As = A + (size_t)(m0 + wid * 32 + rsub) * 2048 + kt * 64 + sch * 8;
    #pragma unroll
    for (int i = 0; i < 4; ++i)
      GLD16(As + (size_t)i * 8 * 2048, base + wid * 4096 + i * 1024);
    // B: wave wid covers rows [wid*16, wid*16+16) as 2 x 8-row loads
    #pragma unroll
    for (int j = 0; j < 2; ++j){
      int rv = n0 + wid * 16 + j * 8 + rsub;
      int rp = (MODE == 0) ? ((rv & ~63) | ((rv & 63) >> 1) | ((rv & 1) << 5)) : rv;
      GLD16(Bw + (size_t)rp * 2048 + kt * 64 + sch * 8, base + 32768 + wid * 2048 + j * 1024);
    }
  };

  f32x4 acc[4][4];
  #pragma unroll
  for (int mi = 0; mi < 4; ++mi)
    #pragma unroll
    for (int ni = 0; ni < 4; ++ni)
      acc[mi][ni] = (f32x4){0.f, 0.f, 0.f, 0.f};

  auto compute = [&](int rb){
    const unsigned char* Ab = lds + rb * BUF;
    const unsigned char* Bb = Ab + 32768;
    bf16x8 af[4][2], bf[4][2];
    #pragma unroll
    for (int mi = 0; mi < 4; ++mi)
      #pragma unroll
      for (int ks = 0; ks < 2; ++ks){
        int r = wr * 64 + mi * 16 + l15, ch = ks * 4 + l4;
        af[mi][ks] = *(const bf16x8*)(Ab + r * 128 + ((ch * 16) ^ ((r & 7) << 4)));
      }
    #pragma unroll
    for (int ni = 0; ni < 4; ++ni)
      #pragma unroll
      for (int ks = 0; ks < 2; ++ks){
        int r = wc * 64 + ni * 16 + l15, ch = ks * 4 + l4;
        bf[ni][ks] = *(const bf16x8*)(Bb + r * 128 + ((ch * 16) ^ ((r & 7) << 4)));
      }
    #pragma unroll
    for (int ks = 0; ks < 2; ++ks)
      #pragma unroll
      for (int mi = 0; mi < 4; ++mi)
        #pragma unroll
        for (int ni = 0; ni < 4; ++ni)
          acc[mi][ni] = __builtin_amdgcn_mfma_f32_16x16x32_bf16(af[mi][ks], bf[ni][ks], acc[mi][ni], 0, 0, 0);
  };

  // prologue: tiles 0,1 staged; wait tile 0 only (tile 1 stays in flight)
  stage(0, 0);
  stage(1, 1);
  asm volatile("s_waitcnt vmcnt(6)" ::: "memory");
  __builtin_amdgcn_s_barrier();
  asm volatile("" ::: "memory");

  // steady state: 30 groups (K = 2048 = 32 tiles of 64)
  #pragma unroll 3
  for (int kt = 0; kt < 30; ++kt){
    stage(kt + 2, (kt + 2) % 3);
    asm volatile("s_waitcnt vmcnt(12)" ::: "memory");
    compute(kt % 3);
    asm volatile("" ::: "memory");
    __builtin_amdgcn_s_barrier();
    asm volatile("" ::: "memory");
  }
  // tail: tile 30 (allow tile 31's 6 loads in flight), then tile 31 (drain)
  asm volatile("s_waitcnt vmcnt(6)" ::: "memory");
  compute(0);
  asm volatile("" ::: "memory");
  __builtin_amdgcn_s_barrier();
  asm volatile("" ::: "memory");
  asm volatile("s_waitcnt vmcnt(0)" ::: "memory");
  compute(1);

  // ---------------- epilogue ----------------
  if (MODE == 1){
    #pragma unroll
    for (int mi = 0; mi < 4; ++mi)
      #pragma unroll
      for (int ni = 0; ni < 4; ++ni)
        #pragma unroll
        for (int j = 0; j < 4; ++j){
          int m = m0 + wr * 64 + mi * 16 + l4 * 4 + j;
          int n = n0 + wc * 64 + ni * 16 + l15;
          Cout[(size_t)m * N + n] = acc[mi][ni][j];
        }
  } else {
    #pragma unroll
    for (int ni = 0; ni < 4; ++ni){
      int e16 = n0 + wc * 64 + ni * 16;          // virtual col base of this frag
      int which = e16 >> 11;                     // 0=q 1=k 2=v (uniform per frag)
      int h = (e16 >> 6) & 31;                   // head (uniform per frag)
      unsigned short* dst = (which == 0) ? Qo : (which == 1) ? Ko : Vo;
      int p = (ni * 16 + l15);                   // virtual in-head position (64-aligned span)
      int d = ((p >> 1) | ((p & 1) << 5));       // physical dim
      #pragma unroll
      for (int mi = 0; mi < 4; ++mi)
        #pragma unroll
        for (int j = 0; j < 4; ++j){
          int m = m0 + wr * 64 + mi * 16 + l4 * 4 + j;   // token = b*2048 + l
          int b = m >> 11, l = m & 2047;
          float val = acc[mi][ni][j];
          float par = SWZ(val, 0x041F);                  // partner = lane^1
          float outv;
          if (which == 2){
            outv = val;
          } else {
            size_t ci = (size_t)(b * 2048 + l) * 64 + d;
            outv = val * cosp[ci] + ((p & 1) ? par : -par) * sinp[ci];
            if (which == 0) outv *= 0.125f;              // fold 1/sqrt(64)
          }
          dst[(size_t)((b * 32 + h) * 2048 + l) * 64 + d] = f2b(outv);
        }
    }
  }
}

// ---------------- V [BH, L, 64] -> Vt [BH, 64, L] ----------------
__global__ __launch_bounds__(256) void transpose_v(const unsigned short* __restrict__ V,
                                                   unsigned short* __restrict__ Vt){
  __shared__ unsigned short tile[64][72];
  int bh = blockIdx.x >> 5;
  int l0 = (blockIdx.x & 31) * 64;
  int t = threadIdx.x;
  #pragma unroll
  for (int i = 0; i < 2; ++i){
    int c = i * 256 + t;
    int row = c >> 3, ch = c & 7;
    uint4 v = *(const uint4*)(V + ((size_t)bh * 2048 + l0 + row) * 64 + ch * 8);
    const unsigned short* p = (const unsigned short*)&v;
    #pragma unroll
    for (int k = 0; k < 8; ++k) tile[row][ch * 8 + k] = p[k];
  }
  __syncthreads();
  #pragma unroll
  for (int i = 0; i < 2; ++i){
    int c = i * 256 + t;
    int drow = c >> 3, ch = c & 7;
    unsigned short tmp[8];
    #pragma unroll
    for (int k = 0; k < 8; ++k) tmp[k] = tile[ch * 8 + k][drow];
    *(uint4*)(Vt + ((size_t)bh * 64 + drow) * 2048 + l0 + ch * 8) = *(const uint4*)tmp;
  }
}

// ---------------- flash attention (causal) ----------------
// Per-wave independent tiles; in-wave qtile pairing (qt, 15-qt) -> identical
// total work per wave regardless of dispatch order. No-max softmax (scores
// bounded; softmax shift-invariant), single cross-lane reduce after k-loop.
__global__ __launch_bounds__(256, 2) void attn_fwd(
    const unsigned short* __restrict__ Q, const unsigned short* __restrict__ K,
    const unsigned short* __restrict__ Vt, unsigned short* __restrict__ Y)
{
  __shared__ __align__(16) unsigned char plds[4][4096];  // per-wave P tile [32][64] bf16, swizzled
  int idx = blockIdx.x;
  int bh = idx >> 3;                  // 8 blocks per bh, contiguous (L2 locality)
  int pr = idx & 7;                   // pair index: handles qtiles pr and 15-pr
  int b = bh >> 5, h = bh & 31;
  int t = threadIdx.x, wid = t >> 6, lane = t & 63;
  int l15 = lane & 15, l4 = lane >> 4;
  const unsigned short* Qb = Q  + (size_t)bh * 2048 * 64;
  const unsigned short* Kb = K  + (size_t)bh * 2048 * 64;
  const unsigned short* Vb = Vt + (size_t)bh * 64 * 2048;
  unsigned char* myp = plds[wid];

  for (int half = 0; half < 2; ++half){
    int qt = half ? (15 - pr) : pr;
    int q0 = qt * 128 + wid * 32;     // 32 q-rows per wave

    bf16x8 aq[2][2];
    #pragma unroll
    for (int mi = 0; mi < 2; ++mi)
      #pragma unroll
      for (int ks = 0; ks < 2; ++ks)
        aq[mi][ks] = *(const bf16x8*)(Qb + (size_t)(q0 + mi * 16 + l15) * 64 + ks * 32 + l4 * 8);

    f32x4 acc[2][4];
    float ps[2][4];
    #pragma unroll
    for (int mi = 0; mi < 2; ++mi){
      #pragma unroll
      for (int nd = 0; nd < 4; ++nd) acc[mi][nd] = (f32x4){0.f, 0.f, 0.f, 0.f};
      #pragma unroll
      for (int j = 0; j < 4; ++j) ps[mi][j] = 0.f;
    }

    int nkt = ((q0 + 31) >> 6) + 1;
    for (int kt = 0; kt < nkt; ++kt){
      int kv0 = kt * 64;
      bf16x8 bk[2][4];
      #pragma unroll
      for (int ks = 0; ks < 2; ++ks)
        #pragma unroll
        for (int ni = 0; ni < 4; ++ni)
          bk[ks][ni] = *(const bf16x8*)(Kb + (size_t)(kv0 + ni * 16 + l15) * 64 + ks * 32 + l4 * 8);
      f32x4 s[2][4];
      #pragma unroll
      for (int mi = 0; mi < 2; ++mi)
        #pragma unroll
        for (int ni = 0; ni < 4; ++ni)
          s[mi][ni] = (f32x4){0.f, 0.f, 0.f, 0.f};
      #pragma unroll
      for (int ks = 0; ks < 2; ++ks)
        #pragma unroll
        for (int mi = 0; mi < 2; ++mi)
          #pragma unroll
          for (int ni = 0; ni < 4; ++ni)
            s[mi][ni] = __builtin_amdgcn_mfma_f32_16x16x32_bf16(aq[mi][ks], bk[ks][ni], s[mi][ni], 0, 0, 0);
      if (kt == nkt - 1){
        #pragma unroll
        for (int mi = 0; mi < 2; ++mi)
          #pragma unroll
          for (int ni = 0; ni < 4; ++ni)
            #pragma unroll
            for (int j = 0; j < 4; ++j){
              int kv = kv0 + ni * 16 + l15;
              int q  = q0 + mi * 16 + l4 * 4 + j;
              if (kv > q) s[mi][ni][j] = -1e30f;
            }
      }
      #pragma unroll
      for (int mi = 0; mi < 2; ++mi)
        #pragma unroll
        for (int ni = 0; ni < 4; ++ni)
          #pragma unroll
          for (int j = 0; j < 4; ++j){
            float p = __expf(s[mi][ni][j]);
            s[mi][ni][j] = p;
            ps[mi][j] += p;
          }
      #pragma unroll
      for (int mi = 0; mi < 2; ++mi)
        #pragma unroll
        for (int j = 0; j < 4; ++j){
          int r = mi * 16 + l4 * 4 + j;
          int sw = (r & 7) << 4;
          unsigned char* rowp = myp + r * 128;
          #pragma unroll
          for (int p2 = 0; p2 < 2; ++p2){
            unsigned int pk;
            asm("v_cvt_pk_bf16_f32 %0, %1, %2" : "=v"(pk) : "v"(s[mi][2 * p2][j]), "v"(s[mi][2 * p2 + 1][j]));
            *(unsigned short*)(rowp + ((p2 * 64      + 2 * l15) ^ sw)) = (unsigned short)pk;
            *(unsigned short*)(rowp + ((p2 * 64 + 32 + 2 * l15) ^ sw)) = (unsigned short)(pk >> 16);
          }
        }
    __threadfence_block();   // wave-local LDS write->read ordering
      #pragma unroll
      for (int ks2 = 0; ks2 < 2; ++ks2){
        bf16x8 ap[2], bv[4];
        #pragma unroll
        for (int mi = 0; mi < 2; ++mi){
          int r = mi * 16 + l15;
          ap[mi] = *(const bf16x8*)(myp + r * 128 + ((ks2 * 64 + l4 * 16) ^ ((r & 7) << 4)));
        }
        #pragma unroll
        for (int nd = 0; nd < 4; ++nd)
          bv[nd] = *(const bf16x8*)(Vb + (size_t)(nd * 16 + l15) * 2048 + kv0 + ks2 * 32 + l4 * 8);
        #pragma unroll
        for (int mi = 0; mi < 2; ++mi)
          #pragma unroll
          for (int nd = 0; nd < 4; ++nd)
            acc[mi][nd] = __builtin_amdgcn_mfma_f32_16x16x32_bf16(ap[mi], bv[nd], acc[mi][nd], 0, 0, 0);
      }
    }
    float lrow[2][4];
    #pragma unroll
    for (int mi = 0; mi < 2; ++mi)
      #pragma unroll
      for (int j = 0; j < 4; ++j){
        float v = ps[mi][j];
        v += SWZ(v, 0x041F);
        v += SWZ(v, 0x081F);
        v += SWZ(v, 0x101F);
        v += SWZ(v, 0x201F);
        lrow[mi][j] = v;
      }
    #pragma unroll
    for (int mi = 0; mi < 2; ++mi){
      float inv[4];
      #pragma unroll
      for (int j = 0; j < 4; ++j) inv[j] = 1.f / lrow[mi][j];
      #pragma unroll
      for (int nd = 0; nd < 4; ++nd)
        #pragma unroll
        for (int j = 0; j < 4; ++j){
          int q = q0 + mi * 16 + l4 * 4 + j;
          int d = nd * 16 + l15;
          Y[(size_t)(b * 2048 + q) * 2048 + h * 64 + d] = f2b(acc[mi][nd][j] * inv[j]);
        }
    }
  }
}

// ---------------- launch ----------------
extern "C" void kernel_launch(void* const* d_in, const int* in_sizes, int n_in,
                              void* d_out, int out_size, void* d_ws, size_t ws_size,
                              hipStream_t stream){
  (void)in_sizes; (void)n_in; (void)out_size; (void)ws_size;
  const float* x     = (const float*)d_in[0];
  const float* cosp  = (const float*)d_in[1];
  const float* sinp  = (const float*)d_in[2];
  const float* Wqkv  = (const float*)d_in[3];
  const float* Wproj = (const float*)d_in[4];
  float* out = (float*)d_out;
  char* ws = (char*)d_ws;

  unsigned short* Xb  = (unsigned short*)(ws);
  unsigned short* Wqb = (unsigned short*)(ws + 16777216);
  unsigned short* Wpb = (unsigned short*)(ws + 41943040);
  unsigned short* Qb  = (unsigned short*)(ws + 50331648);
  unsigned short* Kb  = (unsigned short*)(ws + 67108864);
  unsigned short* Vb  = (unsigned short*)(ws + 83886080);
  unsigned short* Vtb = Xb;   // alias: Xb dead after GEMM1
  unsigned short* Yb  = Vb;   // alias: V dead after transpose

  cvt_all<<<2048, 256, 0, stream>>>(x, Wqkv, Wproj, Xb, Wqb, Wpb);

  // QKV GEMM + RoPE: M=4096 (16 m-tiles), N=6144 (48 n-tiles) -> 768 blocks = 3 exact rounds
  gemm_r3<0><<<768, 512, 0, stream>>>(Xb, Wqb, 48, cosp, sinp, Qb, Kb, Vb, nullptr, 0);
  transpose_v<<<2048, 256, 0, stream>>>(Vb, Vtb);
  attn_fwd<<<512, 256, 0, stream>>>(Qb, Kb, Vtb, Yb);
  // out proj: M=4096, N=2048 (16 n-tiles) -> 256 blocks = 1 exact round
  gemm_r3<1><<<256, 512, 0, stream>>>(Yb, Wpb, 16, nullptr, nullptr, nullptr, nullptr, nullptr, out, 2048);
}